// Round 1
// baseline (843.952 us; speedup 1.0000x reference)
//
#include <hip/hip_runtime.h>

typedef unsigned short u16;
typedef __attribute__((ext_vector_type(4))) float f32x4;
typedef __attribute__((ext_vector_type(8))) short s16x8;
typedef __attribute__((ext_vector_type(4))) short s16x4;

__device__ __forceinline__ u16 f2bf(float f) {
  unsigned u = __float_as_uint(f);
  u += 0x7FFFu + ((u >> 16) & 1u);
  return (u16)(u >> 16);
}
__device__ __forceinline__ float bf2f(u16 h) {
  return __uint_as_float(((unsigned)h) << 16);
}

// ---------------- cast + hi/lo split ----------------
__global__ __launch_bounds__(256) void k_cast_split(
    const float* __restrict__ src, u16* __restrict__ hi, u16* __restrict__ lo, int n4) {
  int i = blockIdx.x * 256 + threadIdx.x;
  if (i >= n4) return;
  f32x4 v = ((const f32x4*)src)[i];
  s16x4 h, l;
#pragma unroll
  for (int e = 0; e < 4; ++e) {
    float f = v[e];
    u16 hb = f2bf(f);
    float r = f - bf2f(hb);
    h[e] = (short)hb;
    l[e] = (short)f2bf(r);
  }
  ((s16x4*)hi)[i] = h;
  ((s16x4*)lo)[i] = l;
}

// ---------------- shared staging helper ----------------
// tile [128 rows][32 k] bf16, padded pitch 40 shorts (80B, 16B-aligned rows)
__device__ __forceinline__ void stage_tile(const u16* __restrict__ g, int ld,
                                           u16 (&s)[128][40], int kOff, int tid) {
#pragma unroll
  for (int it = 0; it < 2; ++it) {
    int c = it * 256 + tid;
    int r = c >> 2, cc = (c & 3) * 8;
    *(s16x8*)&s[r][cc] = *(const s16x8*)(g + (size_t)r * ld + kOff + cc);
  }
}

// ---------------- split GEMM, C = (Ah+Al) * (Bh+Bl)^T ----------------
// EPI 0: QKV epilogue (cols 0-511 -> qh/ql, 512-1023 -> kh/kl, 1024-2047 -> v bf16)
// EPI 1: scores epilogue (fp32 * scale, per-batch z)
template <int EPI>
__global__ __launch_bounds__(256, 2) void k_gemm_bt_split(
    const u16* __restrict__ Ah, const u16* __restrict__ Al, int lda,
    const u16* __restrict__ Bh, const u16* __restrict__ Bl, int ldb, int K,
    u16* __restrict__ qh, u16* __restrict__ ql,
    u16* __restrict__ kh, u16* __restrict__ kl, u16* __restrict__ vv,
    float* __restrict__ sc, float scale) {
  if (EPI == 1) {
    size_t o = (size_t)blockIdx.z * 2048;
    Ah += o * lda; Al += o * lda; Bh += o * ldb; Bl += o * ldb;
    sc += (size_t)blockIdx.z * 2048 * 2048;
  }
  __shared__ u16 sAh[128][40], sAl[128][40], sBh[128][40], sBl[128][40];
  const int tid = threadIdx.x;
  const int lane = tid & 63, wid = tid >> 6;
  const int wr = wid >> 1, wc = wid & 1;
  const int bn = blockIdx.x, bm = blockIdx.y;
  const u16* A0h = Ah + (size_t)bm * 128 * lda;
  const u16* A0l = Al + (size_t)bm * 128 * lda;
  const u16* B0h = Bh + (size_t)bn * 128 * ldb;
  const u16* B0l = Bl + (size_t)bn * 128 * ldb;
  const int fr = lane & 15, fk = (lane >> 4) * 8;
  f32x4 acc[4][4] = {};
  for (int kt = 0; kt < K; kt += 32) {
    __syncthreads();
    stage_tile(A0h, lda, sAh, kt, tid);
    stage_tile(A0l, lda, sAl, kt, tid);
    stage_tile(B0h, ldb, sBh, kt, tid);
    stage_tile(B0l, ldb, sBl, kt, tid);
    __syncthreads();
    s16x8 ah[4], al[4], bh[4], bl[4];
#pragma unroll
    for (int m = 0; m < 4; ++m) {
      ah[m] = *(const s16x8*)&sAh[wr * 64 + m * 16 + fr][fk];
      al[m] = *(const s16x8*)&sAl[wr * 64 + m * 16 + fr][fk];
    }
#pragma unroll
    for (int n = 0; n < 4; ++n) {
      bh[n] = *(const s16x8*)&sBh[wc * 64 + n * 16 + fr][fk];
      bl[n] = *(const s16x8*)&sBl[wc * 64 + n * 16 + fr][fk];
    }
#pragma unroll
    for (int m = 0; m < 4; ++m)
#pragma unroll
      for (int n = 0; n < 4; ++n) {
        acc[m][n] = __builtin_amdgcn_mfma_f32_16x16x32_bf16(ah[m], bh[n], acc[m][n], 0, 0, 0);
        acc[m][n] = __builtin_amdgcn_mfma_f32_16x16x32_bf16(ah[m], bl[n], acc[m][n], 0, 0, 0);
        acc[m][n] = __builtin_amdgcn_mfma_f32_16x16x32_bf16(al[m], bh[n], acc[m][n], 0, 0, 0);
      }
  }
#pragma unroll
  for (int m = 0; m < 4; ++m)
#pragma unroll
    for (int n = 0; n < 4; ++n)
#pragma unroll
      for (int r = 0; r < 4; ++r) {
        int row = bm * 128 + wr * 64 + m * 16 + (lane >> 4) * 4 + r;
        int col = bn * 128 + wc * 64 + n * 16 + fr;
        float f = acc[m][n][r];
        if (EPI == 0) {
          if (col < 512) {
            u16 h = f2bf(f);
            qh[(size_t)row * 512 + col] = h;
            ql[(size_t)row * 512 + col] = f2bf(f - bf2f(h));
          } else if (col < 1024) {
            u16 h = f2bf(f);
            kh[(size_t)row * 512 + col - 512] = h;
            kl[(size_t)row * 512 + col - 512] = f2bf(f - bf2f(h));
          } else {
            vv[(size_t)row * 1024 + col - 1024] = f2bf(f);
          }
        } else {
          sc[(size_t)row * 2048 + col] = f * scale;
        }
      }
}

// ---------------- row softmax + dropout mask, P bf16 written in-place ----------------
__global__ __launch_bounds__(256) void k_softmax(float* __restrict__ sc,
                                                 const int* __restrict__ mask, int bBase) {
  const int rowp = blockIdx.x;  // 0..4095 (2 batches x 2048 rows)
  const int bz = rowp >> 11, t = rowp & 2047;
  float* srow = sc + (size_t)rowp * 2048;
  const int* mrow = mask + ((size_t)(bBase + bz) * 2048 + t) * 2048;
  const int tid = threadIdx.x;
  float v[8];
#pragma unroll
  for (int j = 0; j < 8; ++j) v[j] = srow[tid + 256 * j];
  float m = v[0];
#pragma unroll
  for (int j = 1; j < 8; ++j) m = fmaxf(m, v[j]);
#pragma unroll
  for (int o = 32; o >= 1; o >>= 1) m = fmaxf(m, __shfl_xor(m, o));
  __shared__ float redm[4], reds[4];
  if ((tid & 63) == 0) redm[tid >> 6] = m;
  __syncthreads();
  m = fmaxf(fmaxf(redm[0], redm[1]), fmaxf(redm[2], redm[3]));
  float e[8], s = 0.f;
#pragma unroll
  for (int j = 0; j < 8; ++j) { e[j] = __expf(v[j] - m); s += e[j]; }
#pragma unroll
  for (int o = 32; o >= 1; o >>= 1) s += __shfl_xor(s, o);
  if ((tid & 63) == 0) reds[tid >> 6] = s;
  __syncthreads();
  s = reds[0] + reds[1] + reds[2] + reds[3];
  const float inv = 1.0f / (0.8f * s);
  u16* prow = (u16*)srow;  // in-place: all reads of this row completed before the barriers above
#pragma unroll
  for (int j = 0; j < 8; ++j) {
    int idx = tid + 256 * j;
    prow[idx] = mrow[idx] ? f2bf(e[j] * inv) : (u16)0;
  }
}

// ---------------- out = P @ V (plain bf16), V transposed through LDS ----------------
__global__ __launch_bounds__(256, 2) void k_pv(const u16* __restrict__ P,
                                               const u16* __restrict__ V,
                                               float* __restrict__ out) {
  __shared__ u16 sP[128][40];
  __shared__ u16 sVt[128][40];
  const int tid = threadIdx.x;
  const int lane = tid & 63, wid = tid >> 6;
  const int wr = wid >> 1, wc = wid & 1;
  const int bn = blockIdx.x, bm = blockIdx.y, bz = blockIdx.z;
  const u16* Pb = P + (size_t)(bz * 2048 + bm * 128) * 4096;  // P pitch 4096 shorts
  const u16* Vb = V + (size_t)bz * 2048 * 1024 + bn * 128;
  const int fr = lane & 15, fk = (lane >> 4) * 8;
  f32x4 acc[4][4] = {};
  for (int kt = 0; kt < 2048; kt += 32) {
    __syncthreads();
    stage_tile(Pb, 4096, sP, kt, tid);
#pragma unroll
    for (int it = 0; it < 4; ++it) {
      int c = it * 256 + tid;
      int r = c >> 5, cc = (c & 31) * 4;
      s16x4 d = *(const s16x4*)(Vb + (size_t)(kt + r) * 1024 + cc);
      sVt[cc + 0][r] = (u16)d[0];
      sVt[cc + 1][r] = (u16)d[1];
      sVt[cc + 2][r] = (u16)d[2];
      sVt[cc + 3][r] = (u16)d[3];
    }
    __syncthreads();
    s16x8 a[4], b[4];
#pragma unroll
    for (int m = 0; m < 4; ++m) a[m] = *(const s16x8*)&sP[wr * 64 + m * 16 + fr][fk];
#pragma unroll
    for (int n = 0; n < 4; ++n) b[n] = *(const s16x8*)&sVt[wc * 64 + n * 16 + fr][fk];
#pragma unroll
    for (int m = 0; m < 4; ++m)
#pragma unroll
      for (int n = 0; n < 4; ++n)
        acc[m][n] = __builtin_amdgcn_mfma_f32_16x16x32_bf16(a[m], b[n], acc[m][n], 0, 0, 0);
  }
  const size_t obase = (size_t)bz * 2048 * 1024;
#pragma unroll
  for (int m = 0; m < 4; ++m)
#pragma unroll
    for (int n = 0; n < 4; ++n)
#pragma unroll
      for (int r = 0; r < 4; ++r) {
        int row = bm * 128 + wr * 64 + m * 16 + (lane >> 4) * 4 + r;
        int col = bn * 128 + wc * 64 + n * 16 + fr;
        out[obase + (size_t)row * 1024 + col] = acc[m][n][r];
      }
}

extern "C" void kernel_launch(void* const* d_in, const int* in_sizes, int n_in,
                              void* d_out, int out_size, void* d_ws, size_t ws_size,
                              hipStream_t stream) {
  const float* x  = (const float*)d_in[0];
  const float* Wq = (const float*)d_in[1];
  const float* Wk = (const float*)d_in[2];
  const float* Wv = (const float*)d_in[3];
  const int* mask = (const int*)d_in[4];
  float* out = (float*)d_out;

  // ws layout (u16 elements). scores (2 batches, fp32) aliases xh/xl which are
  // dead after the QKV GEMM.
  u16* ws = (u16*)d_ws;
  u16* xh = ws;                               // 16384x1024
  u16* xl = xh + (size_t)16777216;
  u16* Wh = xl + (size_t)16777216;            // 2048x1024 (Wq|Wk|Wv)
  u16* Wl = Wh + (size_t)2097152;
  u16* qh = Wl + (size_t)2097152;             // 16384x512
  u16* ql = qh + (size_t)8388608;
  u16* kh = ql + (size_t)8388608;
  u16* kl = kh + (size_t)8388608;
  u16* vv = kl + (size_t)8388608;             // 16384x1024
  float* sc = (float*)d_ws;                   // 2x2048x2048 fp32, aliased

  k_cast_split<<<16384, 256, 0, stream>>>(x, xh, xl, 4194304);
  k_cast_split<<<512, 256, 0, stream>>>(Wq, Wh, Wl, 131072);
  k_cast_split<<<512, 256, 0, stream>>>(Wk, Wh + 524288, Wl + 524288, 131072);
  k_cast_split<<<1024, 256, 0, stream>>>(Wv, Wh + 1048576, Wl + 1048576, 262144);

  dim3 g2(16, 128, 1);
  k_gemm_bt_split<0><<<g2, 256, 0, stream>>>(xh, xl, 1024, Wh, Wl, 1024, 1024,
                                             qh, ql, kh, kl, vv, (float*)0, 0.f);

  const float scale = 0.044194173824159216f;  // 1/sqrt(512)
  for (int bp = 0; bp < 4; ++bp) {
    size_t qo = (size_t)bp * 2 * 2048 * 512;
    dim3 g3(16, 16, 2);
    k_gemm_bt_split<1><<<g3, 256, 0, stream>>>(qh + qo, ql + qo, 512, kh + qo, kl + qo, 512, 512,
                                               (u16*)0, (u16*)0, (u16*)0, (u16*)0, (u16*)0,
                                               sc, scale);
    k_softmax<<<4096, 256, 0, stream>>>(sc, mask, bp * 2);
    dim3 g5(8, 16, 2);
    k_pv<<<g5, 256, 0, stream>>>((const u16*)sc, vv + (size_t)bp * 2 * 2048 * 1024,
                                 out + (size_t)bp * 2 * 2048 * 1024);
  }
  (void)in_sizes; (void)n_in; (void)out_size; (void)ws_size;
}

// Round 2
// 520.274 us; speedup vs baseline: 1.6221x; 1.6221x over previous
//
#include <hip/hip_runtime.h>

typedef unsigned short u16;
typedef __attribute__((ext_vector_type(4))) float f32x4;
typedef __attribute__((ext_vector_type(8))) short s16x8;
typedef __attribute__((ext_vector_type(4))) short s16x4;

__device__ __forceinline__ u16 f2bf(float f) {
  unsigned u = __float_as_uint(f);
  u += 0x7FFFu + ((u >> 16) & 1u);
  return (u16)(u >> 16);
}
__device__ __forceinline__ float bf2f(u16 h) {
  return __uint_as_float(((unsigned)h) << 16);
}

// ---------------- cast + hi/lo split ----------------
__global__ __launch_bounds__(256) void k_cast_split(
    const float* __restrict__ src, u16* __restrict__ hi, u16* __restrict__ lo, int n4) {
  int i = blockIdx.x * 256 + threadIdx.x;
  if (i >= n4) return;
  f32x4 v = ((const f32x4*)src)[i];
  s16x4 h, l;
#pragma unroll
  for (int e = 0; e < 4; ++e) {
    float f = v[e];
    u16 hb = f2bf(f);
    float r = f - bf2f(hb);
    h[e] = (short)hb;
    l[e] = (short)f2bf(r);
  }
  ((s16x4*)hi)[i] = h;
  ((s16x4*)lo)[i] = l;
}

__global__ __launch_bounds__(256) void k_cast_plain(
    const float* __restrict__ src, u16* __restrict__ dst, int n4) {
  int i = blockIdx.x * 256 + threadIdx.x;
  if (i >= n4) return;
  f32x4 v = ((const f32x4*)src)[i];
  s16x4 h;
#pragma unroll
  for (int e = 0; e < 4; ++e) h[e] = (short)f2bf(v[e]);
  ((s16x4*)dst)[i] = h;
}

// ---------------- shared staging helper ----------------
// tile [128 rows][32 k] bf16, padded pitch 40 shorts (80B, 16B-aligned rows)
__device__ __forceinline__ void stage_tile(const u16* __restrict__ g, int ld,
                                           u16 (&s)[128][40], int kOff, int tid) {
#pragma unroll
  for (int it = 0; it < 2; ++it) {
    int c = it * 256 + tid;
    int r = c >> 2, cc = (c & 3) * 8;
    *(s16x8*)&s[r][cc] = *(const s16x8*)(g + (size_t)r * ld + kOff + cc);
  }
}

// ---------------- B^T GEMM, C = A * B^T, NT split terms ----------------
// NT=3: A,B given as hi+lo, acc += Ah*Bh + Ah*Bl + Al*Bh
// NT=1: plain bf16.
// EPI 0: bf16 store C[row*ldc+col]
// EPI 1: fp32 store C[row*ldc+col] = f*scale
// EPI 2: qk slab split store (row in [0,16384), col in [0,1024))
template <int NT, int EPI>
__global__ __launch_bounds__(256, 2) void k_gemm_bt(
    const u16* __restrict__ Ah, const u16* __restrict__ Al, int lda, long long aZ,
    const u16* __restrict__ Bh, const u16* __restrict__ Bl, int ldb, long long bZ,
    int K, void* __restrict__ Cp, int ldc, long long cZ, float scale) {
  __shared__ u16 sAh[128][40];
  __shared__ u16 sBh[128][40];
  __shared__ u16 sAl[NT == 3 ? 128 : 1][40];
  __shared__ u16 sBl[NT == 3 ? 128 : 1][40];
  const int tid = threadIdx.x;
  const int lane = tid & 63, wid = tid >> 6;
  const int wr = wid >> 1, wc = wid & 1;
  const int bn = blockIdx.x, bm = blockIdx.y, bz = blockIdx.z;
  const u16* A0h = Ah + (size_t)bz * aZ + (size_t)bm * 128 * lda;
  const u16* B0h = Bh + (size_t)bz * bZ + (size_t)bn * 128 * ldb;
  const u16* A0l = Al ? Al + (size_t)bz * aZ + (size_t)bm * 128 * lda : A0h;
  const u16* B0l = Bl ? Bl + (size_t)bz * bZ + (size_t)bn * 128 * ldb : B0h;
  const int fr = lane & 15, fk = (lane >> 4) * 8;
  f32x4 acc[4][4] = {};
  for (int kt = 0; kt < K; kt += 32) {
    __syncthreads();
    stage_tile(A0h, lda, sAh, kt, tid);
    stage_tile(B0h, ldb, sBh, kt, tid);
    if constexpr (NT == 3) {
      stage_tile(A0l, lda, sAl, kt, tid);
      stage_tile(B0l, ldb, sBl, kt, tid);
    }
    __syncthreads();
    s16x8 ah[4], bh[4];
    s16x8 al[4], bl[4];
#pragma unroll
    for (int m = 0; m < 4; ++m) {
      ah[m] = *(const s16x8*)&sAh[wr * 64 + m * 16 + fr][fk];
      if constexpr (NT == 3) al[m] = *(const s16x8*)&sAl[wr * 64 + m * 16 + fr][fk];
    }
#pragma unroll
    for (int n = 0; n < 4; ++n) {
      bh[n] = *(const s16x8*)&sBh[wc * 64 + n * 16 + fr][fk];
      if constexpr (NT == 3) bl[n] = *(const s16x8*)&sBl[wc * 64 + n * 16 + fr][fk];
    }
#pragma unroll
    for (int m = 0; m < 4; ++m)
#pragma unroll
      for (int n = 0; n < 4; ++n) {
        acc[m][n] = __builtin_amdgcn_mfma_f32_16x16x32_bf16(ah[m], bh[n], acc[m][n], 0, 0, 0);
        if constexpr (NT == 3) {
          acc[m][n] = __builtin_amdgcn_mfma_f32_16x16x32_bf16(ah[m], bl[n], acc[m][n], 0, 0, 0);
          acc[m][n] = __builtin_amdgcn_mfma_f32_16x16x32_bf16(al[m], bh[n], acc[m][n], 0, 0, 0);
        }
      }
  }
  const size_t zc = (size_t)bz * cZ;
#pragma unroll
  for (int m = 0; m < 4; ++m)
#pragma unroll
    for (int n = 0; n < 4; ++n)
#pragma unroll
      for (int r = 0; r < 4; ++r) {
        int row = bm * 128 + wr * 64 + m * 16 + (lane >> 4) * 4 + r;
        int col = bn * 128 + wc * 64 + n * 16 + fr;
        float f = acc[m][n][r];
        if constexpr (EPI == 0) {
          ((u16*)Cp)[zc + (size_t)row * ldc + col] = f2bf(f);
        } else if constexpr (EPI == 1) {
          ((float*)Cp)[zc + (size_t)row * ldc + col] = f * scale;
        } else {
          // qk slab: 4 batch-pair slabs of 8,388,608 u16 each:
          // [qh 2097152 | ql 2097152 | kh 2097152 | kl 2097152]
          int bp = row >> 12;
          int rl = row & 4095;
          u16* slab = (u16*)Cp + (size_t)bp * 8388608;
          u16 h = f2bf(f);
          u16 l = f2bf(f - bf2f(h));
          if (col < 512) {
            slab[(size_t)rl * 512 + col] = h;
            slab[2097152 + (size_t)rl * 512 + col] = l;
          } else {
            slab[4194304 + (size_t)rl * 512 + (col - 512)] = h;
            slab[6291456 + (size_t)rl * 512 + (col - 512)] = l;
          }
        }
      }
}

// ---------------- row softmax + dropout mask -> P bf16 ----------------
__global__ __launch_bounds__(256) void k_softmax(const float* __restrict__ sc,
                                                 u16* __restrict__ P,
                                                 const int* __restrict__ mask, int bBase) {
  const int rowp = blockIdx.x;  // 0..4095 (2 batches x 2048 rows)
  const int bz = rowp >> 11, t = rowp & 2047;
  const float* srow = sc + (size_t)rowp * 2048;
  u16* prow = P + (size_t)rowp * 2048;
  const int* mrow = mask + ((size_t)(bBase + bz) * 2048 + t) * 2048;
  const int tid = threadIdx.x;
  float v[8];
#pragma unroll
  for (int j = 0; j < 8; ++j) v[j] = srow[tid + 256 * j];
  float m = v[0];
#pragma unroll
  for (int j = 1; j < 8; ++j) m = fmaxf(m, v[j]);
#pragma unroll
  for (int o = 32; o >= 1; o >>= 1) m = fmaxf(m, __shfl_xor(m, o));
  __shared__ float redm[4], reds[4];
  if ((tid & 63) == 0) redm[tid >> 6] = m;
  __syncthreads();
  m = fmaxf(fmaxf(redm[0], redm[1]), fmaxf(redm[2], redm[3]));
  float e[8], s = 0.f;
#pragma unroll
  for (int j = 0; j < 8; ++j) { e[j] = __expf(v[j] - m); s += e[j]; }
#pragma unroll
  for (int o = 32; o >= 1; o >>= 1) s += __shfl_xor(s, o);
  if ((tid & 63) == 0) reds[tid >> 6] = s;
  __syncthreads();
  s = reds[0] + reds[1] + reds[2] + reds[3];
  const float inv = 1.0f / (0.8f * s);
#pragma unroll
  for (int j = 0; j < 8; ++j) {
    int idx = tid + 256 * j;
    prow[idx] = mrow[idx] ? f2bf(e[j] * inv) : (u16)0;
  }
}

extern "C" void kernel_launch(void* const* d_in, const int* in_sizes, int n_in,
                              void* d_out, int out_size, void* d_ws, size_t ws_size,
                              hipStream_t stream) {
  const float* x  = (const float*)d_in[0];
  const float* Wq = (const float*)d_in[1];
  const float* Wk = (const float*)d_in[2];
  const float* Wv = (const float*)d_in[3];
  const int* mask = (const int*)d_in[4];
  float* out = (float*)d_out;

  // ws layout (u16 elements), total ~174 MB:
  u16* ws = (u16*)d_ws;
  u16* xh     = ws;                           // 16384x1024
  u16* xl     = xh + (size_t)16777216;
  u16* Whqk   = xl + (size_t)16777216;        // 1024x1024 (Wq rows 0-511 | Wk rows 512-1023)
  u16* Wlqk   = Whqk + (size_t)1048576;
  u16* Wvh    = Wlqk + (size_t)1048576;       // 1024x1024 plain bf16
  u16* qkslab = Wvh + (size_t)1048576;        // 4 slabs x 8388608 (later: P, 8x2048x2048)
  u16* vvt    = qkslab + (size_t)33554432;    // 1024 x 16384 (v^T, all batches)
  float* sc   = (float*)d_ws;                 // 2x2048x2048 fp32 scratch, aliases xh/xl
                                              // (dead after the two GEMMs below)

  k_cast_split<<<16384, 256, 0, stream>>>(x, xh, xl, 4194304);
  k_cast_split<<<512, 256, 0, stream>>>(Wq, Whqk, Wlqk, 131072);
  k_cast_split<<<512, 256, 0, stream>>>(Wk, Whqk + 524288, Wlqk + 524288, 131072);
  k_cast_plain<<<1024, 256, 0, stream>>>(Wv, Wvh, 262144);

  // q,k = x @ [Wq|Wk]^T  (3-term split), stored hi/lo into per-bp slabs
  dim3 gqk(8, 128, 1);
  k_gemm_bt<3, 2><<<gqk, 256, 0, stream>>>(xh, xl, 1024, 0, Whqk, Wlqk, 1024, 0,
                                           1024, qkslab, 0, 0, 0.f);

  // v^T = Wv @ x^T (plain bf16): C[g][t], coalesced, no transpose needed later
  dim3 gvt(128, 8, 1);
  k_gemm_bt<1, 0><<<gvt, 256, 0, stream>>>(Wvh, (u16*)0, 1024, 0, xh, (u16*)0, 1024, 0,
                                           1024, vvt, 16384, 0, 0.f);

  const float scale = 0.044194173824159216f;  // 1/sqrt(512)
  for (int bp = 0; bp < 4; ++bp) {
    u16* slab = qkslab + (size_t)bp * 8388608;
    dim3 gs(16, 16, 2);
    k_gemm_bt<3, 1><<<gs, 256, 0, stream>>>(slab, slab + 2097152, 512, 1048576,
                                            slab + 4194304, slab + 6291456, 512, 1048576,
                                            512, sc, 2048, 4194304, scale);
    // softmax overwrites the (now dead) q/k slab with P bf16
    k_softmax<<<4096, 256, 0, stream>>>(sc, slab, mask, bp * 2);
  }

  // out = P @ (v^T)^T for all 8 batches in one launch
  dim3 gpv(8, 16, 8);
  k_gemm_bt<1, 1><<<gpv, 256, 0, stream>>>(qkslab, (u16*)0, 2048, 4194304,
                                           vvt, (u16*)0, 16384, 2048,
                                           2048, out, 1024, 2097152, 1.0f);

  (void)in_sizes; (void)n_in; (void)out_size; (void)ws_size;
}

// Round 3
// 481.116 us; speedup vs baseline: 1.7542x; 1.0814x over previous
//
#include <hip/hip_runtime.h>

typedef unsigned short u16;
typedef __attribute__((ext_vector_type(4))) float f32x4;
typedef __attribute__((ext_vector_type(8))) short s16x8;
typedef __attribute__((ext_vector_type(4))) short s16x4;

__device__ __forceinline__ u16 f2bf(float f) {
  unsigned u = __float_as_uint(f);
  u += 0x7FFFu + ((u >> 16) & 1u);
  return (u16)(u >> 16);
}
__device__ __forceinline__ float bf2f(u16 h) {
  return __uint_as_float(((unsigned)h) << 16);
}

// ---------------- cast + hi/lo split ----------------
__global__ __launch_bounds__(256) void k_cast_split(
    const float* __restrict__ src, u16* __restrict__ hi, u16* __restrict__ lo, int n4) {
  int i = blockIdx.x * 256 + threadIdx.x;
  if (i >= n4) return;
  f32x4 v = ((const f32x4*)src)[i];
  s16x4 h, l;
#pragma unroll
  for (int e = 0; e < 4; ++e) {
    float f = v[e];
    u16 hb = f2bf(f);
    float r = f - bf2f(hb);
    h[e] = (short)hb;
    l[e] = (short)f2bf(r);
  }
  ((s16x4*)hi)[i] = h;
  ((s16x4*)lo)[i] = l;
}

__global__ __launch_bounds__(256) void k_cast_plain(
    const float* __restrict__ src, u16* __restrict__ dst, int n4) {
  int i = blockIdx.x * 256 + threadIdx.x;
  if (i >= n4) return;
  f32x4 v = ((const f32x4*)src)[i];
  s16x4 h;
#pragma unroll
  for (int e = 0; e < 4; ++e) h[e] = (short)f2bf(v[e]);
  ((s16x4*)dst)[i] = h;
}

// ---------------- async global->LDS staging ----------------
__device__ __forceinline__ void gl16(const u16* src, u16* dst) {
  __builtin_amdgcn_global_load_lds(
      (const __attribute__((address_space(1))) unsigned*)src,
      (__attribute__((address_space(3))) unsigned*)dst, 16, 0, 0);
}

// stage a [128][32] u16 LINEAR tile (8 KB): 2 x global_load_lds_dwordx4 per wave.
// LDS dest must be wave-uniform base + lane*16B (m104): rows r0..r0+15, 64B/row.
__device__ __forceinline__ void stage_lds(const u16* __restrict__ g, int ld, u16* s,
                                          int kOff, int wid, int lane) {
#pragma unroll
  for (int i = 0; i < 2; ++i) {
    int r0 = wid * 32 + i * 16;
    gl16(g + (size_t)(r0 + (lane >> 2)) * ld + kOff + (lane & 3) * 8, s + r0 * 32);
  }
}

// XCD-chunked bijective block swizzle (T1). Requires total blocks % 8 == 0
// (all GEMM grids here are 512 or 1024).
__device__ __forceinline__ void swz_block(int& bn, int& bm, int& bz) {
  int gx = gridDim.x, gy = gridDim.y;
  int flat = blockIdx.x + gx * (blockIdx.y + gy * blockIdx.z);
  int nwg = gx * gy * (int)gridDim.z;
  int q = nwg >> 3;
  int id = (flat & 7) * q + (flat >> 3);
  bn = id % gx;
  id /= gx;
  bm = id % gy;
  bz = id / gy;
}

// ---------------- B^T GEMM, C = A * B^T, NT split terms ----------------
// NT=3: A,B given as hi+lo, acc += Ah*Bh + Ah*Bl + Al*Bh
// NT=1: plain bf16.
// EPI 0: bf16 store C[row*ldc+col]
// EPI 1: fp32 store C[row*ldc+col] = f*scale
// EPI 2: qk slab split store (row in [0,16384), col in [0,1024))
template <int NT, int EPI>
__global__ __launch_bounds__(256, 2) void k_gemm_bt(
    const u16* __restrict__ Ah, const u16* __restrict__ Al, int lda, long long aZ,
    const u16* __restrict__ Bh, const u16* __restrict__ Bl, int ldb, long long bZ,
    int K, void* __restrict__ Cp, int ldc, long long cZ, float scale) {
  __shared__ u16 sAh[128 * 32];
  __shared__ u16 sBh[128 * 32];
  __shared__ u16 sAl[NT == 3 ? 128 * 32 : 16];
  __shared__ u16 sBl[NT == 3 ? 128 * 32 : 16];
  int bn, bm, bz;
  swz_block(bn, bm, bz);
  const int tid = threadIdx.x;
  const int lane = tid & 63, wid = tid >> 6;
  const int wr = wid >> 1, wc = wid & 1;
  const u16* A0h = Ah + (size_t)bz * aZ + (size_t)bm * 128 * lda;
  const u16* B0h = Bh + (size_t)bz * bZ + (size_t)bn * 128 * ldb;
  const u16* A0l = Al ? Al + (size_t)bz * aZ + (size_t)bm * 128 * lda : A0h;
  const u16* B0l = Bl ? Bl + (size_t)bz * bZ + (size_t)bn * 128 * ldb : B0h;
  const int fr = lane & 15, fk = (lane >> 4) * 8;
  f32x4 acc[4][4] = {};
  for (int kt = 0; kt < K; kt += 32) {
    __syncthreads();  // prior iteration's ds_reads done before overwrite
    stage_lds(A0h, lda, sAh, kt, wid, lane);
    stage_lds(B0h, ldb, sBh, kt, wid, lane);
    if constexpr (NT == 3) {
      stage_lds(A0l, lda, sAl, kt, wid, lane);
      stage_lds(B0l, ldb, sBl, kt, wid, lane);
    }
    __syncthreads();  // compiler drains vmcnt before s_barrier
    s16x8 ah[4], bh[4];
    s16x8 al[4], bl[4];
#pragma unroll
    for (int m = 0; m < 4; ++m) {
      ah[m] = *(const s16x8*)&sAh[(wr * 64 + m * 16 + fr) * 32 + fk];
      if constexpr (NT == 3) al[m] = *(const s16x8*)&sAl[(wr * 64 + m * 16 + fr) * 32 + fk];
    }
#pragma unroll
    for (int n = 0; n < 4; ++n) {
      bh[n] = *(const s16x8*)&sBh[(wc * 64 + n * 16 + fr) * 32 + fk];
      if constexpr (NT == 3) bl[n] = *(const s16x8*)&sBl[(wc * 64 + n * 16 + fr) * 32 + fk];
    }
#pragma unroll
    for (int m = 0; m < 4; ++m)
#pragma unroll
      for (int n = 0; n < 4; ++n) {
        acc[m][n] = __builtin_amdgcn_mfma_f32_16x16x32_bf16(ah[m], bh[n], acc[m][n], 0, 0, 0);
        if constexpr (NT == 3) {
          acc[m][n] = __builtin_amdgcn_mfma_f32_16x16x32_bf16(ah[m], bl[n], acc[m][n], 0, 0, 0);
          acc[m][n] = __builtin_amdgcn_mfma_f32_16x16x32_bf16(al[m], bh[n], acc[m][n], 0, 0, 0);
        }
      }
  }
  const size_t zc = (size_t)bz * cZ;
#pragma unroll
  for (int m = 0; m < 4; ++m)
#pragma unroll
    for (int n = 0; n < 4; ++n)
#pragma unroll
      for (int r = 0; r < 4; ++r) {
        int row = bm * 128 + wr * 64 + m * 16 + (lane >> 4) * 4 + r;
        int col = bn * 128 + wc * 64 + n * 16 + fr;
        float f = acc[m][n][r];
        if constexpr (EPI == 0) {
          ((u16*)Cp)[zc + (size_t)row * ldc + col] = f2bf(f);
        } else if constexpr (EPI == 1) {
          ((float*)Cp)[zc + (size_t)row * ldc + col] = f * scale;
        } else {
          // qk slab: 4 batch-pair slabs of 8,388,608 u16 each:
          // [qh 2097152 | ql 2097152 | kh 2097152 | kl 2097152]
          int bp = row >> 12;
          int rl = row & 4095;
          u16* slab = (u16*)Cp + (size_t)bp * 8388608;
          u16 h = f2bf(f);
          u16 l = f2bf(f - bf2f(h));
          if (col < 512) {
            slab[(size_t)rl * 512 + col] = h;
            slab[2097152 + (size_t)rl * 512 + col] = l;
          } else {
            slab[4194304 + (size_t)rl * 512 + (col - 512)] = h;
            slab[6291456 + (size_t)rl * 512 + (col - 512)] = l;
          }
        }
      }
}

// ---------------- row softmax + dropout mask -> P bf16 ----------------
__global__ __launch_bounds__(256) void k_softmax(const float* __restrict__ sc,
                                                 u16* __restrict__ P,
                                                 const int* __restrict__ mask, int bBase) {
  const int rowp = blockIdx.x;  // 0..4095 (2 batches x 2048 rows)
  const int bz = rowp >> 11, t = rowp & 2047;
  const float* srow = sc + (size_t)rowp * 2048;
  u16* prow = P + (size_t)rowp * 2048;
  const int* mrow = mask + ((size_t)(bBase + bz) * 2048 + t) * 2048;
  const int tid = threadIdx.x;
  float v[8];
#pragma unroll
  for (int j = 0; j < 8; ++j) v[j] = srow[tid + 256 * j];
  float m = v[0];
#pragma unroll
  for (int j = 1; j < 8; ++j) m = fmaxf(m, v[j]);
#pragma unroll
  for (int o = 32; o >= 1; o >>= 1) m = fmaxf(m, __shfl_xor(m, o));
  __shared__ float redm[4], reds[4];
  if ((tid & 63) == 0) redm[tid >> 6] = m;
  __syncthreads();
  m = fmaxf(fmaxf(redm[0], redm[1]), fmaxf(redm[2], redm[3]));
  float e[8], s = 0.f;
#pragma unroll
  for (int j = 0; j < 8; ++j) { e[j] = __expf(v[j] - m); s += e[j]; }
#pragma unroll
  for (int o = 32; o >= 1; o >>= 1) s += __shfl_xor(s, o);
  if ((tid & 63) == 0) reds[tid >> 6] = s;
  __syncthreads();
  s = reds[0] + reds[1] + reds[2] + reds[3];
  const float inv = 1.0f / (0.8f * s);
#pragma unroll
  for (int j = 0; j < 8; ++j) {
    int idx = tid + 256 * j;
    prow[idx] = mrow[idx] ? f2bf(e[j] * inv) : (u16)0;
  }
}

extern "C" void kernel_launch(void* const* d_in, const int* in_sizes, int n_in,
                              void* d_out, int out_size, void* d_ws, size_t ws_size,
                              hipStream_t stream) {
  const float* x  = (const float*)d_in[0];
  const float* Wq = (const float*)d_in[1];
  const float* Wk = (const float*)d_in[2];
  const float* Wv = (const float*)d_in[3];
  const int* mask = (const int*)d_in[4];
  float* out = (float*)d_out;

  // ws layout (u16 elements), total ~174 MB:
  u16* ws = (u16*)d_ws;
  u16* xh     = ws;                           // 16384x1024
  u16* xl     = xh + (size_t)16777216;
  u16* Whqk   = xl + (size_t)16777216;        // 1024x1024 (Wq rows 0-511 | Wk rows 512-1023)
  u16* Wlqk   = Whqk + (size_t)1048576;
  u16* Wvh    = Wlqk + (size_t)1048576;       // 1024x1024 plain bf16
  u16* qkslab = Wvh + (size_t)1048576;        // 4 slabs x 8388608 (later: P, 8x2048x2048)
  u16* vvt    = qkslab + (size_t)33554432;    // 1024 x 16384 (v^T, all batches)
  float* sc   = (float*)d_ws;                 // 2x2048x2048 fp32 scratch, aliases xh/xl
                                              // (dead after the two GEMMs below)

  k_cast_split<<<16384, 256, 0, stream>>>(x, xh, xl, 4194304);
  k_cast_split<<<512, 256, 0, stream>>>(Wq, Whqk, Wlqk, 131072);
  k_cast_split<<<512, 256, 0, stream>>>(Wk, Whqk + 524288, Wlqk + 524288, 131072);
  k_cast_plain<<<1024, 256, 0, stream>>>(Wv, Wvh, 262144);

  // q,k = x @ [Wq|Wk]^T  (3-term split), stored hi/lo into per-bp slabs
  dim3 gqk(8, 128, 1);
  k_gemm_bt<3, 2><<<gqk, 256, 0, stream>>>(xh, xl, 1024, 0, Whqk, Wlqk, 1024, 0,
                                           1024, qkslab, 0, 0, 0.f);

  // v^T = Wv @ x^T (plain bf16): C[g][t], coalesced, no transpose needed later
  dim3 gvt(128, 8, 1);
  k_gemm_bt<1, 0><<<gvt, 256, 0, stream>>>(Wvh, (u16*)0, 1024, 0, xh, (u16*)0, 1024, 0,
                                           1024, vvt, 16384, 0, 0.f);

  const float scale = 0.044194173824159216f;  // 1/sqrt(512)
  for (int bp = 0; bp < 4; ++bp) {
    u16* slab = qkslab + (size_t)bp * 8388608;
    dim3 gs(16, 16, 2);
    k_gemm_bt<3, 1><<<gs, 256, 0, stream>>>(slab, slab + 2097152, 512, 1048576,
                                            slab + 4194304, slab + 6291456, 512, 1048576,
                                            512, sc, 2048, 4194304, scale);
    // softmax overwrites the (now dead) q/k slab with P bf16
    k_softmax<<<4096, 256, 0, stream>>>(sc, slab, mask, bp * 2);
  }

  // out = P @ (v^T)^T for all 8 batches in one launch
  dim3 gpv(8, 16, 8);
  k_gemm_bt<1, 1><<<gpv, 256, 0, stream>>>(qkslab, (u16*)0, 2048, 4194304,
                                           vvt, (u16*)0, 16384, 2048,
                                           2048, out, 1024, 2097152, 1.0f);

  (void)in_sizes; (void)n_in; (void)out_size; (void)ws_size;
}

// Round 4
// 446.692 us; speedup vs baseline: 1.8893x; 1.0771x over previous
//
#include <hip/hip_runtime.h>

typedef unsigned short u16;
typedef __attribute__((ext_vector_type(4))) float f32x4;
typedef __attribute__((ext_vector_type(8))) short s16x8;
typedef __attribute__((ext_vector_type(4))) short s16x4;

__device__ __forceinline__ u16 f2bf(float f) {
  unsigned u = __float_as_uint(f);
  u += 0x7FFFu + ((u >> 16) & 1u);
  return (u16)(u >> 16);
}
__device__ __forceinline__ float bf2f(u16 h) {
  return __uint_as_float(((unsigned)h) << 16);
}

// ---------------- cast + hi/lo split ----------------
__global__ __launch_bounds__(256) void k_cast_split(
    const float* __restrict__ src, u16* __restrict__ hi, u16* __restrict__ lo, int n4) {
  int i = blockIdx.x * 256 + threadIdx.x;
  if (i >= n4) return;
  f32x4 v = ((const f32x4*)src)[i];
  s16x4 h, l;
#pragma unroll
  for (int e = 0; e < 4; ++e) {
    float f = v[e];
    u16 hb = f2bf(f);
    float r = f - bf2f(hb);
    h[e] = (short)hb;
    l[e] = (short)f2bf(r);
  }
  ((s16x4*)hi)[i] = h;
  ((s16x4*)lo)[i] = l;
}

__global__ __launch_bounds__(256) void k_cast_plain(
    const float* __restrict__ src, u16* __restrict__ dst, int n4) {
  int i = blockIdx.x * 256 + threadIdx.x;
  if (i >= n4) return;
  f32x4 v = ((const f32x4*)src)[i];
  s16x4 h;
#pragma unroll
  for (int e = 0; e < 4; ++e) h[e] = (short)f2bf(v[e]);
  ((s16x4*)dst)[i] = h;
}

// ---------------- async global->LDS staging ----------------
__device__ __forceinline__ void gl16(const u16* src, u16* dst) {
  __builtin_amdgcn_global_load_lds(
      (const __attribute__((address_space(1))) unsigned*)src,
      (__attribute__((address_space(3))) unsigned*)dst, 16, 0, 0);
}

// stage a [256][32] u16 LINEAR tile (16 KB): 2 gload_lds_dwordx4 per wave (8 waves).
__device__ __forceinline__ void stage_lds(const u16* __restrict__ g, int ld, u16* s,
                                          int kOff, int wid, int lane) {
#pragma unroll
  for (int i = 0; i < 2; ++i) {
    int r0 = wid * 32 + i * 16;
    gl16(g + (size_t)(r0 + (lane >> 2)) * ld + kOff + (lane & 3) * 8, s + r0 * 32);
  }
}

// XCD-chunked bijective block swizzle (T1). Total blocks % 8 == 0 everywhere here.
__device__ __forceinline__ void swz_block(int& bn, int& bm, int& bz) {
  int gx = gridDim.x, gy = gridDim.y;
  int flat = blockIdx.x + gx * (blockIdx.y + gy * blockIdx.z);
  int nwg = gx * gy * (int)gridDim.z;
  int q = nwg >> 3;
  int id = (flat & 7) * q + (flat >> 3);
  bn = id % gx;
  id /= gx;
  bm = id % gy;
  bz = id / gy;
}

// ---------------- B^T GEMM, C = A * B^T, 256x256 block, 8 waves, dbuf 2-phase ----
// wave tile 128x64 (m=8, n=4). NT=3: acc += Ah*Bh + Ah*Bl + Al*Bh. NT=1: plain.
// EPI 0: bf16 store   EPI 1: fp32 store *scale   EPI 2: qkv slab split store
// EPI 3: scores (z in [0,4): batch = slab (z>>1), half (z&1); fp32 *scale)
template <int NT, int EPI>
__global__ __launch_bounds__(512, 2) void k_gemm(
    const u16* __restrict__ Ah, const u16* __restrict__ Al, int lda, long long aZ,
    const u16* __restrict__ Bh, const u16* __restrict__ Bl, int ldb, long long bZ,
    int K, void* __restrict__ Cp, int ldc, long long cZ, float scale) {
  __shared__ u16 sA[2][NT == 3 ? 2 : 1][256 * 32];
  __shared__ u16 sB[2][NT == 3 ? 2 : 1][256 * 32];
  int bn, bm, bz;
  swz_block(bn, bm, bz);
  const int tid = threadIdx.x;
  const int lane = tid & 63, wid = tid >> 6;
  const int wr = wid >> 2, wc = wid & 3;  // 2 x 4 wave grid
  const u16 *A0h, *A0l = nullptr, *B0h, *B0l = nullptr;
  if constexpr (EPI == 3) {
    // Ah = base of a 2-slab (4-batch) group laid out [qh|ql|kh|kl] per slab
    size_t zo = (size_t)(bz >> 1) * 8388608 + (size_t)(bz & 1) * 1048576;
    A0h = Ah + zo + (size_t)bm * 256 * 512;
    A0l = A0h + 2097152;
    B0h = Ah + zo + 4194304 + (size_t)bn * 256 * 512;
    B0l = B0h + 2097152;
  } else {
    A0h = Ah + (size_t)bz * aZ + (size_t)bm * 256 * lda;
    B0h = Bh + (size_t)bz * bZ + (size_t)bn * 256 * ldb;
    if constexpr (NT == 3) {
      A0l = Al + (size_t)bz * aZ + (size_t)bm * 256 * lda;
      B0l = Bl + (size_t)bz * bZ + (size_t)bn * 256 * ldb;
    }
  }
  const int fr = lane & 15, fk = (lane >> 4) * 8;

  auto STAGE = [&](int buf, int kt) {
    stage_lds(A0h, lda, sA[buf][0], kt, wid, lane);
    stage_lds(B0h, ldb, sB[buf][0], kt, wid, lane);
    if constexpr (NT == 3) {
      stage_lds(A0l, lda, sA[buf][1], kt, wid, lane);
      stage_lds(B0l, ldb, sB[buf][1], kt, wid, lane);
    }
  };

  f32x4 acc[8][4] = {};
  STAGE(0, 0);
  __syncthreads();  // drains vmcnt: tile 0 resident
  int cur = 0;
  for (int kt = 0; kt < K; kt += 32) {
    if (kt + 32 < K) STAGE(cur ^ 1, kt + 32);  // issue next-tile loads FIRST
    s16x8 bh[4], bl[4];
#pragma unroll
    for (int n = 0; n < 4; ++n) {
      bh[n] = *(const s16x8*)&sB[cur][0][(wc * 64 + n * 16 + fr) * 32 + fk];
      if constexpr (NT == 3)
        bl[n] = *(const s16x8*)&sB[cur][1][(wc * 64 + n * 16 + fr) * 32 + fk];
    }
#pragma unroll
    for (int m = 0; m < 8; ++m) {
      s16x8 ah = *(const s16x8*)&sA[cur][0][(wr * 128 + m * 16 + fr) * 32 + fk];
      s16x8 al;
      if constexpr (NT == 3)
        al = *(const s16x8*)&sA[cur][1][(wr * 128 + m * 16 + fr) * 32 + fk];
#pragma unroll
      for (int n = 0; n < 4; ++n) {
        acc[m][n] = __builtin_amdgcn_mfma_f32_16x16x32_bf16(ah, bh[n], acc[m][n], 0, 0, 0);
        if constexpr (NT == 3) {
          acc[m][n] = __builtin_amdgcn_mfma_f32_16x16x32_bf16(ah, bl[n], acc[m][n], 0, 0, 0);
          acc[m][n] = __builtin_amdgcn_mfma_f32_16x16x32_bf16(al, bh[n], acc[m][n], 0, 0, 0);
        }
      }
    }
    __syncthreads();  // waits this iter's gload_lds (next tile) + all reads of cur
    cur ^= 1;
  }

  const size_t zc = (size_t)bz * cZ;
#pragma unroll
  for (int m = 0; m < 8; ++m)
#pragma unroll
    for (int n = 0; n < 4; ++n)
#pragma unroll
      for (int r = 0; r < 4; ++r) {
        int row = bm * 256 + wr * 128 + m * 16 + (lane >> 4) * 4 + r;
        int col = bn * 256 + wc * 64 + n * 16 + fr;
        float f = acc[m][n][r];
        if constexpr (EPI == 0) {
          ((u16*)Cp)[zc + (size_t)row * ldc + col] = f2bf(f);
        } else if constexpr (EPI == 1) {
          ((float*)Cp)[zc + (size_t)row * ldc + col] = f * scale;
        } else if constexpr (EPI == 3) {
          ((float*)Cp)[zc + (size_t)row * ldc + col] = f * scale;
        } else {
          // qkv slab: 4 batch-pair slabs of 8,388,608 u16: [qh|ql|kh|kl]
          int bp = row >> 12;
          int rl = row & 4095;
          u16* slab = (u16*)Cp + (size_t)bp * 8388608;
          u16 h = f2bf(f);
          u16 l = f2bf(f - bf2f(h));
          if (col < 512) {
            slab[(size_t)rl * 512 + col] = h;
            slab[2097152 + (size_t)rl * 512 + col] = l;
          } else {
            slab[4194304 + (size_t)rl * 512 + (col - 512)] = h;
            slab[6291456 + (size_t)rl * 512 + (col - 512)] = l;
          }
        }
      }
}

// ---------------- row softmax + dropout mask -> P bf16 (4 batches / dispatch) ----
__global__ __launch_bounds__(256) void k_softmax(const float* __restrict__ sc,
                                                 u16* __restrict__ P,
                                                 const int* __restrict__ mask, int bp2) {
  const int rowp = blockIdx.x;  // 0..8191 (4 batches x 2048 rows)
  const int b = bp2 * 4 + (rowp >> 11), t = rowp & 2047;
  const float* srow = sc + (size_t)rowp * 2048;
  u16* prow = P + (size_t)b * 4194304 + (size_t)t * 2048;
  const int* mrow = mask + ((size_t)b * 2048 + t) * 2048;
  const int tid = threadIdx.x;
  float v[8];
#pragma unroll
  for (int j = 0; j < 8; ++j) v[j] = srow[tid + 256 * j];
  float m = v[0];
#pragma unroll
  for (int j = 1; j < 8; ++j) m = fmaxf(m, v[j]);
#pragma unroll
  for (int o = 32; o >= 1; o >>= 1) m = fmaxf(m, __shfl_xor(m, o));
  __shared__ float redm[4], reds[4];
  if ((tid & 63) == 0) redm[tid >> 6] = m;
  __syncthreads();
  m = fmaxf(fmaxf(redm[0], redm[1]), fmaxf(redm[2], redm[3]));
  float e[8], s = 0.f;
#pragma unroll
  for (int j = 0; j < 8; ++j) { e[j] = __expf(v[j] - m); s += e[j]; }
#pragma unroll
  for (int o = 32; o >= 1; o >>= 1) s += __shfl_xor(s, o);
  if ((tid & 63) == 0) reds[tid >> 6] = s;
  __syncthreads();
  s = reds[0] + reds[1] + reds[2] + reds[3];
  const float inv = 1.0f / (0.8f * s);
#pragma unroll
  for (int j = 0; j < 8; ++j) {
    int idx = tid + 256 * j;
    prow[idx] = mrow[idx] ? f2bf(e[j] * inv) : (u16)0;
  }
}

extern "C" void kernel_launch(void* const* d_in, const int* in_sizes, int n_in,
                              void* d_out, int out_size, void* d_ws, size_t ws_size,
                              hipStream_t stream) {
  const float* x  = (const float*)d_in[0];
  const float* Wq = (const float*)d_in[1];
  const float* Wk = (const float*)d_in[2];
  const float* Wv = (const float*)d_in[3];
  const int* mask = (const int*)d_in[4];
  float* out = (float*)d_out;

  // ws layout (u16 elements), total ~174 MB:
  u16* ws = (u16*)d_ws;
  u16* xh     = ws;                           // 16384x1024
  u16* xl     = xh + (size_t)16777216;
  u16* Whqk   = xl + (size_t)16777216;        // 1024x1024 (Wq rows 0-511 | Wk rows 512-1023)
  u16* Wlqk   = Whqk + (size_t)1048576;
  u16* Wvh    = Wlqk + (size_t)1048576;       // 1024x1024 plain bf16
  u16* qkslab = Wvh + (size_t)1048576;        // 4 slabs x 8388608 (later: P, 8x2048x2048)
  u16* vvt    = qkslab + (size_t)33554432;    // 1024 x 16384 (v^T, all batches)
  float* sc   = (float*)d_ws;                 // 4x2048x2048 fp32 = 67 MB, aliases xh+xl
                                              // (dead after QKV + vT GEMMs)

  k_cast_split<<<16384, 256, 0, stream>>>(x, xh, xl, 4194304);
  k_cast_split<<<512, 256, 0, stream>>>(Wq, Whqk, Wlqk, 131072);
  k_cast_split<<<512, 256, 0, stream>>>(Wk, Whqk + 524288, Wlqk + 524288, 131072);
  k_cast_plain<<<1024, 256, 0, stream>>>(Wv, Wvh, 262144);

  // q,k = x @ [Wq|Wk]^T (3-term split) -> per-bp slabs
  dim3 gqk(4, 64, 1);
  k_gemm<3, 2><<<gqk, 512, 0, stream>>>(xh, xl, 1024, 0, Whqk, Wlqk, 1024, 0,
                                        1024, qkslab, 0, 0, 0.f);

  // v^T = Wv @ x^T (plain bf16): C[g][t], coalesced
  dim3 gvt(64, 4, 1);
  k_gemm<1, 0><<<gvt, 512, 0, stream>>>(Wvh, (u16*)0, 1024, 0, xh, (u16*)0, 1024, 0,
                                        1024, vvt, 16384, 0, 0.f);

  const float scale = 0.044194173824159216f;  // 1/sqrt(512)
  for (int bp2 = 0; bp2 < 2; ++bp2) {
    // scores for 4 batches (2 slabs), 3-term split, z in [0,4)
    dim3 gs(8, 8, 4);
    k_gemm<3, 3><<<gs, 512, 0, stream>>>(qkslab + (size_t)bp2 * 16777216, (u16*)0, 512, 0,
                                         (u16*)0, (u16*)0, 512, 0,
                                         512, sc, 2048, 4194304, scale);
    // softmax overwrites the (now dead) q/k slabs with P bf16 (linear per batch)
    k_softmax<<<8192, 256, 0, stream>>>(sc, qkslab, mask, bp2);
  }

  // out = P @ (v^T)^T for all 8 batches in one launch
  dim3 gpv(4, 8, 8);
  k_gemm<1, 1><<<gpv, 512, 0, stream>>>(qkslab, (u16*)0, 2048, 4194304,
                                        vvt, (u16*)0, 16384, 2048,
                                        2048, out, 1024, 2097152, 1.0f);

  (void)in_sizes; (void)n_in; (void)out_size; (void)ws_size;
}

// Round 5
// 424.615 us; speedup vs baseline: 1.9876x; 1.0520x over previous
//
#include <hip/hip_runtime.h>

typedef unsigned short u16;
typedef __attribute__((ext_vector_type(4))) float f32x4;
typedef __attribute__((ext_vector_type(8))) short s16x8;
typedef __attribute__((ext_vector_type(4))) short s16x4;

__device__ __forceinline__ u16 f2bf(float f) {
  unsigned u = __float_as_uint(f);
  u += 0x7FFFu + ((u >> 16) & 1u);
  return (u16)(u >> 16);
}
__device__ __forceinline__ float bf2f(u16 h) {
  return __uint_as_float(((unsigned)h) << 16);
}

// ---------------- cast + hi/lo split ----------------
__global__ __launch_bounds__(256) void k_cast_split(
    const float* __restrict__ src, u16* __restrict__ hi, u16* __restrict__ lo, int n4) {
  int i = blockIdx.x * 256 + threadIdx.x;
  if (i >= n4) return;
  f32x4 v = ((const f32x4*)src)[i];
  s16x4 h, l;
#pragma unroll
  for (int e = 0; e < 4; ++e) {
    float f = v[e];
    u16 hb = f2bf(f);
    float r = f - bf2f(hb);
    h[e] = (short)hb;
    l[e] = (short)f2bf(r);
  }
  ((s16x4*)hi)[i] = h;
  ((s16x4*)lo)[i] = l;
}

__global__ __launch_bounds__(256) void k_cast_plain(
    const float* __restrict__ src, u16* __restrict__ dst, int n4) {
  int i = blockIdx.x * 256 + threadIdx.x;
  if (i >= n4) return;
  f32x4 v = ((const f32x4*)src)[i];
  s16x4 h;
#pragma unroll
  for (int e = 0; e < 4; ++e) h[e] = (short)f2bf(v[e]);
  ((s16x4*)dst)[i] = h;
}

// ---------------- async global->LDS ----------------
__device__ __forceinline__ void gl16(const u16* src, u16* dst) {
  __builtin_amdgcn_global_load_lds(
      (const __attribute__((address_space(1))) unsigned*)src,
      (__attribute__((address_space(3))) unsigned*)dst, 16, 0, 0);
}

// Stage one 32 KB slot: A[256][32] at slot[0..8192), B[256][32] at slot[8192..16384).
// LDS dest is LINEAR (gload_lds writes base+lane*16); the XOR swizzle
// chunk^=(row>>1)&3 is applied by permuting the per-lane GLOBAL source (rule #21),
// and again on the ds_read side. 4 gl16 per wave.
__device__ __forceinline__ void stage_slot(const u16* __restrict__ gA, int lda,
                                           const u16* __restrict__ gB, int ldb,
                                           u16* slot, int kOff, int wid, int lane) {
  const int co = (((lane & 3) ^ ((lane >> 3) & 3)) << 3);  // swizzled chunk, elems
  const int rr = lane >> 2;
#pragma unroll
  for (int i = 0; i < 2; ++i) {
    int r0 = wid * 32 + i * 16;
    int r = r0 + rr;
    gl16(gA + (size_t)r * lda + kOff + co, slot + r0 * 32);
    gl16(gB + (size_t)r * ldb + kOff + co, slot + 8192 + r0 * 32);
  }
}

// XCD-chunked bijective block swizzle (T1). Total blocks % 8 == 0 everywhere here.
__device__ __forceinline__ void swz_block(int& bn, int& bm, int& bz) {
  int gx = gridDim.x, gy = gridDim.y;
  int flat = blockIdx.x + gx * (blockIdx.y + gy * blockIdx.z);
  int nwg = gx * gy * (int)gridDim.z;
  int q = nwg >> 3;
  int id = (flat & 7) * q + (flat >> 3);
  bn = id % gx;
  id /= gx;
  bm = id % gy;
  bz = id / gy;
}

// ---------------- B^T GEMM, 256x256 block, 8 waves (2x4), wave tile 128x64 -------
// Split-as-K: K_eff = NSEG*SK; seg0 Ah*Bh, seg1 Ah*Bl, seg2 Al*Bh.
// Ring-of-3 LDS slots, counted vmcnt (tile t+2 staged during tile t; barrier never
// drains to 0 in the main loop).
// EPI 0: bf16 store  EPI 1: fp32 store *scale  EPI 2: qkv slab split  EPI 3: scores
template <int NSEG, int SK, int EPI>
__global__ __launch_bounds__(512, 2) void k_gemm(
    const u16* __restrict__ Ah, const u16* __restrict__ Al, int lda, long long aZ,
    const u16* __restrict__ Bh, const u16* __restrict__ Bl, int ldb, long long bZ,
    void* __restrict__ Cp, int ldc, long long cZ, float scale) {
  __shared__ u16 lds[3][16384];
  int bn, bm, bz;
  swz_block(bn, bm, bz);
  const int tid = threadIdx.x;
  const int lane = tid & 63, wid = tid >> 6;
  const int wr = wid >> 2, wc = wid & 3;
  const u16 *A0h, *A0l = nullptr, *B0h, *B0l = nullptr;
  if constexpr (EPI == 3) {
    // Ah = base of a 2-slab (4-batch) group; slabs laid out [qh|ql|kh|kl]
    size_t zo = (size_t)(bz >> 1) * 8388608 + (size_t)(bz & 1) * 1048576;
    A0h = Ah + zo + (size_t)bm * 256 * 512;
    A0l = A0h + 2097152;
    B0h = Ah + zo + 4194304 + (size_t)bn * 256 * 512;
    B0l = B0h + 2097152;
  } else {
    A0h = Ah + (size_t)bz * aZ + (size_t)bm * 256 * lda;
    B0h = Bh + (size_t)bz * bZ + (size_t)bn * 256 * ldb;
    if constexpr (NSEG == 3) {
      A0l = Al + (size_t)bz * aZ + (size_t)bm * 256 * lda;
      B0l = Bl + (size_t)bz * bZ + (size_t)bn * 256 * ldb;
    }
  }
  const int fr = lane & 15;
  const int pc = (((lane >> 4) ^ ((lane >> 1) & 3)) << 3);  // swizzled read chunk
  constexpr int TPS = SK >> 5;          // tiles per segment
  constexpr int NTILES = NSEG * TPS;

  auto STAGE = [&](int slot, int t) {
    int seg = t / TPS;                  // constexpr divisor (power of 2)
    int kk = (t - seg * TPS) << 5;
    const u16* gA = (NSEG == 3 && seg == 2) ? A0l : A0h;
    const u16* gB = (NSEG == 3 && seg == 1) ? B0l : B0h;
    stage_slot(gA, lda, gB, ldb, &lds[slot][0], kk, wid, lane);
  };

  f32x4 acc[8][4] = {};
  STAGE(0, 0);
  STAGE(1, 1);
  asm volatile("s_waitcnt vmcnt(4)" ::: "memory");  // tile 0 resident (oldest 4)
  __builtin_amdgcn_s_barrier();
  asm volatile("" ::: "memory");
  int cur = 0;
  for (int t = 0; t < NTILES; ++t) {
    int nslot = cur + 2;
    if (nslot >= 3) nslot -= 3;
    if (t + 2 < NTILES) STAGE(nslot, t + 2);  // into slot freed at end of t-1
    const u16* sl = &lds[0][0] + cur * 16384;
    s16x8 a[8], b[4];
#pragma unroll
    for (int n = 0; n < 4; ++n)
      b[n] = *(const s16x8*)&sl[8192 + (wc * 64 + n * 16 + fr) * 32 + pc];
#pragma unroll
    for (int m = 0; m < 8; ++m)
      a[m] = *(const s16x8*)&sl[(wr * 128 + m * 16 + fr) * 32 + pc];
    __builtin_amdgcn_s_setprio(1);
#pragma unroll
    for (int m = 0; m < 8; ++m)
#pragma unroll
      for (int n = 0; n < 4; ++n)
        acc[m][n] = __builtin_amdgcn_mfma_f32_16x16x32_bf16(a[m], b[n], acc[m][n], 0, 0, 0);
    __builtin_amdgcn_s_setprio(0);
    // tile t+1 must be resident for next iter; keep tile t+2's 4 loads in flight
    if (t + 2 < NTILES)
      asm volatile("s_waitcnt vmcnt(4)" ::: "memory");
    else
      asm volatile("s_waitcnt vmcnt(0)" ::: "memory");
    __builtin_amdgcn_s_barrier();
    asm volatile("" ::: "memory");
    cur = cur + 1;
    if (cur >= 3) cur -= 3;
  }

  const size_t zc = (size_t)bz * cZ;
#pragma unroll
  for (int m = 0; m < 8; ++m)
#pragma unroll
    for (int n = 0; n < 4; ++n)
#pragma unroll
      for (int r = 0; r < 4; ++r) {
        int row = bm * 256 + wr * 128 + m * 16 + (lane >> 4) * 4 + r;
        int col = bn * 256 + wc * 64 + n * 16 + fr;
        float f = acc[m][n][r];
        if constexpr (EPI == 0) {
          ((u16*)Cp)[zc + (size_t)row * ldc + col] = f2bf(f);
        } else if constexpr (EPI == 1 || EPI == 3) {
          ((float*)Cp)[zc + (size_t)row * ldc + col] = f * scale;
        } else {
          // qkv slab: 4 batch-pair slabs of 8,388,608 u16: [qh|ql|kh|kl]
          int bp = row >> 12;
          int rl = row & 4095;
          u16* slab = (u16*)Cp + (size_t)bp * 8388608;
          u16 h = f2bf(f);
          u16 l = f2bf(f - bf2f(h));
          if (col < 512) {
            slab[(size_t)rl * 512 + col] = h;
            slab[2097152 + (size_t)rl * 512 + col] = l;
          } else {
            slab[4194304 + (size_t)rl * 512 + (col - 512)] = h;
            slab[6291456 + (size_t)rl * 512 + (col - 512)] = l;
          }
        }
      }
}

// ---------------- row softmax + dropout mask -> P bf16 (4 batches / dispatch) ----
__global__ __launch_bounds__(256) void k_softmax(const float* __restrict__ sc,
                                                 u16* __restrict__ P,
                                                 const int* __restrict__ mask, int bp2) {
  const int rowp = blockIdx.x;  // 0..8191 (4 batches x 2048 rows)
  const int b = bp2 * 4 + (rowp >> 11), t = rowp & 2047;
  const float* srow = sc + (size_t)rowp * 2048;
  u16* prow = P + (size_t)b * 4194304 + (size_t)t * 2048;
  const int* mrow = mask + ((size_t)b * 2048 + t) * 2048;
  const int tid = threadIdx.x;
  float v[8];
#pragma unroll
  for (int j = 0; j < 8; ++j) v[j] = srow[tid + 256 * j];
  float m = v[0];
#pragma unroll
  for (int j = 1; j < 8; ++j) m = fmaxf(m, v[j]);
#pragma unroll
  for (int o = 32; o >= 1; o >>= 1) m = fmaxf(m, __shfl_xor(m, o));
  __shared__ float redm[4], reds[4];
  if ((tid & 63) == 0) redm[tid >> 6] = m;
  __syncthreads();
  m = fmaxf(fmaxf(redm[0], redm[1]), fmaxf(redm[2], redm[3]));
  float e[8], s = 0.f;
#pragma unroll
  for (int j = 0; j < 8; ++j) { e[j] = __expf(v[j] - m); s += e[j]; }
#pragma unroll
  for (int o = 32; o >= 1; o >>= 1) s += __shfl_xor(s, o);
  if ((tid & 63) == 0) reds[tid >> 6] = s;
  __syncthreads();
  s = reds[0] + reds[1] + reds[2] + reds[3];
  const float inv = 1.0f / (0.8f * s);
#pragma unroll
  for (int j = 0; j < 8; ++j) {
    int idx = tid + 256 * j;
    prow[idx] = mrow[idx] ? f2bf(e[j] * inv) : (u16)0;
  }
}

extern "C" void kernel_launch(void* const* d_in, const int* in_sizes, int n_in,
                              void* d_out, int out_size, void* d_ws, size_t ws_size,
                              hipStream_t stream) {
  const float* x  = (const float*)d_in[0];
  const float* Wq = (const float*)d_in[1];
  const float* Wk = (const float*)d_in[2];
  const float* Wv = (const float*)d_in[3];
  const int* mask = (const int*)d_in[4];
  float* out = (float*)d_out;

  // ws layout (u16 elements), total ~174 MB:
  u16* ws = (u16*)d_ws;
  u16* xh     = ws;                           // 16384x1024
  u16* xl     = xh + (size_t)16777216;
  u16* Whqk   = xl + (size_t)16777216;        // 1024x1024 (Wq rows 0-511 | Wk rows 512-1023)
  u16* Wlqk   = Whqk + (size_t)1048576;
  u16* Wvh    = Wlqk + (size_t)1048576;       // 1024x1024 plain bf16
  u16* qkslab = Wvh + (size_t)1048576;        // 4 slabs x 8388608 (later: P, 8x2048x2048)
  u16* vvt    = qkslab + (size_t)33554432;    // 1024 x 16384 (v^T, all batches)
  float* sc   = (float*)d_ws;                 // 4x2048x2048 fp32 = 67 MB, aliases xh+xl
                                              // (dead after QKV + vT GEMMs)

  k_cast_split<<<16384, 256, 0, stream>>>(x, xh, xl, 4194304);
  k_cast_split<<<512, 256, 0, stream>>>(Wq, Whqk, Wlqk, 131072);
  k_cast_split<<<512, 256, 0, stream>>>(Wk, Whqk + 524288, Wlqk + 524288, 131072);
  k_cast_plain<<<1024, 256, 0, stream>>>(Wv, Wvh, 262144);

  // q,k = x @ [Wq|Wk]^T  (3-term split folded into K: K_eff = 3072)
  dim3 gqk(4, 64, 1);
  k_gemm<3, 1024, 2><<<gqk, 512, 0, stream>>>(xh, xl, 1024, 0, Whqk, Wlqk, 1024, 0,
                                              qkslab, 0, 0, 0.f);

  // v^T = Wv @ x^T (plain bf16): C[g][t], coalesced
  dim3 gvt(64, 4, 1);
  k_gemm<1, 1024, 0><<<gvt, 512, 0, stream>>>(Wvh, (u16*)0, 1024, 0, xh, (u16*)0, 1024, 0,
                                              vvt, 16384, 0, 0.f);

  const float scale = 0.044194173824159216f;  // 1/sqrt(512)
  for (int bp2 = 0; bp2 < 2; ++bp2) {
    // scores for 4 batches (2 slabs), split-as-K (K_eff = 1536), z in [0,4)
    dim3 gs(8, 8, 4);
    k_gemm<3, 512, 3><<<gs, 512, 0, stream>>>(qkslab + (size_t)bp2 * 16777216, (u16*)0, 512, 0,
                                              (u16*)0, (u16*)0, 512, 0,
                                              sc, 2048, 4194304, scale);
    // softmax overwrites the (now dead) q/k slabs with P bf16 (linear per batch)
    k_softmax<<<8192, 256, 0, stream>>>(sc, qkslab, mask, bp2);
  }

  // out = P @ (v^T)^T for all 8 batches in one launch
  dim3 gpv(4, 8, 8);
  k_gemm<1, 2048, 1><<<gpv, 512, 0, stream>>>(qkslab, (u16*)0, 2048, 4194304,
                                              vvt, (u16*)0, 16384, 2048,
                                              out, 1024, 2097152, 1.0f);

  (void)in_sizes; (void)n_in; (void)out_size; (void)ws_size;
}

// Round 6
// 423.180 us; speedup vs baseline: 1.9943x; 1.0034x over previous
//
#include <hip/hip_runtime.h>

typedef unsigned short u16;
typedef __attribute__((ext_vector_type(4))) float f32x4;
typedef __attribute__((ext_vector_type(8))) short s16x8;
typedef __attribute__((ext_vector_type(4))) short s16x4;

__device__ __forceinline__ u16 f2bf(float f) {
  unsigned u = __float_as_uint(f);
  u += 0x7FFFu + ((u >> 16) & 1u);
  return (u16)(u >> 16);
}
__device__ __forceinline__ float bf2f(u16 h) {
  return __uint_as_float(((unsigned)h) << 16);
}

// ---------------- cast + hi/lo split ----------------
__global__ __launch_bounds__(256) void k_cast_split(
    const float* __restrict__ src, u16* __restrict__ hi, u16* __restrict__ lo, int n4) {
  int i = blockIdx.x * 256 + threadIdx.x;
  if (i >= n4) return;
  f32x4 v = ((const f32x4*)src)[i];
  s16x4 h, l;
#pragma unroll
  for (int e = 0; e < 4; ++e) {
    float f = v[e];
    u16 hb = f2bf(f);
    float r = f - bf2f(hb);
    h[e] = (short)hb;
    l[e] = (short)f2bf(r);
  }
  ((s16x4*)hi)[i] = h;
  ((s16x4*)lo)[i] = l;
}

__global__ __launch_bounds__(256) void k_cast_plain(
    const float* __restrict__ src, u16* __restrict__ dst, int n4) {
  int i = blockIdx.x * 256 + threadIdx.x;
  if (i >= n4) return;
  f32x4 v = ((const f32x4*)src)[i];
  s16x4 h;
#pragma unroll
  for (int e = 0; e < 4; ++e) h[e] = (short)f2bf(v[e]);
  ((s16x4*)dst)[i] = h;
}

// ---------------- async global->LDS ----------------
__device__ __forceinline__ void gl16(const u16* src, u16* dst) {
  __builtin_amdgcn_global_load_lds(
      (const __attribute__((address_space(1))) unsigned*)src,
      (__attribute__((address_space(3))) unsigned*)dst, 16, 0, 0);
}

// XCD-chunked bijective block swizzle (T1). Total blocks % 8 == 0 everywhere here.
__device__ __forceinline__ void swz_block(int& bn, int& bm, int& bz) {
  int gx = gridDim.x, gy = gridDim.y;
  int flat = blockIdx.x + gx * (blockIdx.y + gy * blockIdx.z);
  int nwg = gx * gy * (int)gridDim.z;
  int q = nwg >> 3;
  int id = (flat & 7) * q + (flat >> 3);
  bn = id % gx;
  id /= gx;
  bm = id % gy;
  bz = id / gy;
}

// ---------------- B^T GEMM, 256x256 block, 8 waves (2x4), 8-phase schedule ------
// Split-as-K: K_eff = NSEG*SK; seg0 Ah*Bh, seg1 Ah*Bl, seg2 Al*Bh.
// K-tile = 64, stored as two contiguous K-half sub-regions [kh][256 rows][32 k]
// per operand per buffer (dbuf, 128 KiB total). Chunk swizzle pc = k8 ^ ((r>>1)&3).
// Per tile: 4 phases {ds_read 4/8 b128, stage 1 half-tile, (q3: vmcnt(6)),
// barrier, lgkmcnt(0), setprio(1), 16 MFMA, setprio(0), barrier}.
// Staging: q0 -> A.kh1 of T+1; q1/q2/q3 -> B.kh0 / A.kh0 / B.kh1 of T+2.
// EPI 0: bf16 store  EPI 1: fp32 store *scale  EPI 2: qkv slab split  EPI 3: scores
template <int NSEG, int SK, int EPI>
__global__ __launch_bounds__(512, 2) void k_gemm(
    const u16* __restrict__ Ah, const u16* __restrict__ Al, int lda, long long aZ,
    const u16* __restrict__ Bh, const u16* __restrict__ Bl, int ldb, long long bZ,
    void* __restrict__ Cp, int ldc, long long cZ, float scale) {
  __shared__ u16 lds[2 * 32768];  // 2 bufs x (A 16384 + B 16384) u16 = 128 KiB
  int bn, bm, bz;
  swz_block(bn, bm, bz);
  const int tid = threadIdx.x;
  const int lane = tid & 63, wid = tid >> 6;
  const int wr = wid >> 2, wc = wid & 3;
  const u16 *A0h, *A0l = nullptr, *B0h, *B0l = nullptr;
  if constexpr (EPI == 3) {
    // Ah = base of a 2-slab (4-batch) group; slabs laid out [qh|ql|kh|kl]
    size_t zo = (size_t)(bz >> 1) * 8388608 + (size_t)(bz & 1) * 1048576;
    A0h = Ah + zo + (size_t)bm * 256 * 512;
    A0l = A0h + 2097152;
    B0h = Ah + zo + 4194304 + (size_t)bn * 256 * 512;
    B0l = B0h + 2097152;
  } else {
    A0h = Ah + (size_t)bz * aZ + (size_t)bm * 256 * lda;
    B0h = Bh + (size_t)bz * bZ + (size_t)bn * 256 * ldb;
    if constexpr (NSEG == 3) {
      A0l = Al + (size_t)bz * aZ + (size_t)bm * 256 * lda;
      B0l = Bl + (size_t)bz * bZ + (size_t)bn * 256 * ldb;
    }
  }
  constexpr int TPS = SK >> 6;  // 64-K tiles per segment
  constexpr int NT = NSEG * TPS;

  // stage one half-tile (16 KB): op 0=A 1=B, K-half kh of tile t -> buf t&1.
  // Linear LDS dest (gload_lds), inverse-swizzled global source (rule #21).
  auto STAGE = [&](int t, int op, int kh) {
    if (t >= NT) return;
    int seg = (NSEG == 3) ? (t / TPS) : 0;
    int kk = ((t - seg * TPS) << 6) + (kh << 5);
    const u16* g;
    int ld_;
    if (op == 0) { g = (NSEG == 3 && seg == 2) ? A0l : A0h; ld_ = lda; }
    else         { g = (NSEG == 3 && seg == 1) ? B0l : B0h; ld_ = ldb; }
    u16* dst = &lds[0] + (t & 1) * 32768 + op * 16384 + kh * 8192;
    int lc = ((tid & 3) ^ ((tid >> 3) & 3)) << 3;
    int r0 = tid >> 2;
    gl16(g + (size_t)r0 * ld_ + kk + lc, dst + tid * 8);
    gl16(g + (size_t)(r0 + 128) * ld_ + kk + lc, dst + 4096 + tid * 8);
  };

  const int fr = lane & 15;
  const int pch = (((lane >> 4) ^ ((fr >> 1) & 3)) << 3);  // physical chunk (elems)
  const int abase = (wr * 128 + fr) * 32 + pch;             // A frag m,kh: +m*512 +kh*8192
  const int bbase = 16384 + (wc * 64 + fr) * 32 + pch;      // B frag n,kh

  f32x4 acc[8][4] = {};

  // prologue: tile0 {Ak0,Ak1,Bk0,Bk1}, tile1 {Bk0,Ak0,Bk1}; tile1.Ak1 comes at (0,q0)
  STAGE(0, 0, 0); STAGE(0, 0, 1); STAGE(0, 1, 0); STAGE(0, 1, 1);
  STAGE(1, 1, 0); STAGE(1, 0, 0); STAGE(1, 1, 1);
  asm volatile("s_waitcnt vmcnt(6)" ::: "memory");  // tile0 (oldest 8 loads) resident
  __builtin_amdgcn_s_barrier();

  auto TILE = [&](int T, int c, bool drain) {
    const int cb = c * 32768;
    s16x8 av[4], bv[4];
    // ---- q0: A m0-3 kh0 + B n0-3 kh0 ----
#pragma unroll
    for (int n = 0; n < 4; ++n) bv[n] = *(const s16x8*)&lds[cb + bbase + n * 512];
#pragma unroll
    for (int m = 0; m < 4; ++m) av[m] = *(const s16x8*)&lds[cb + abase + m * 512];
    STAGE(T + 1, 0, 1);
    __builtin_amdgcn_s_barrier();
    asm volatile("s_waitcnt lgkmcnt(0)" ::: "memory");
    __builtin_amdgcn_s_setprio(1);
#pragma unroll
    for (int m = 0; m < 4; ++m)
#pragma unroll
      for (int n = 0; n < 4; ++n)
        acc[m][n] = __builtin_amdgcn_mfma_f32_16x16x32_bf16(av[m], bv[n], acc[m][n], 0, 0, 0);
    __builtin_amdgcn_s_setprio(0);
    __builtin_amdgcn_s_barrier();
    // ---- q1: A m4-7 kh0 (B kh0 reused) ----
#pragma unroll
    for (int m = 0; m < 4; ++m) av[m] = *(const s16x8*)&lds[cb + abase + 2048 + m * 512];
    STAGE(T + 2, 1, 0);
    __builtin_amdgcn_s_barrier();
    asm volatile("s_waitcnt lgkmcnt(0)" ::: "memory");
    __builtin_amdgcn_s_setprio(1);
#pragma unroll
    for (int m = 0; m < 4; ++m)
#pragma unroll
      for (int n = 0; n < 4; ++n)
        acc[m + 4][n] = __builtin_amdgcn_mfma_f32_16x16x32_bf16(av[m], bv[n], acc[m + 4][n], 0, 0, 0);
    __builtin_amdgcn_s_setprio(0);
    __builtin_amdgcn_s_barrier();
    // ---- q2: A m0-3 kh1 + B n0-3 kh1 ----
#pragma unroll
    for (int n = 0; n < 4; ++n) bv[n] = *(const s16x8*)&lds[cb + bbase + 8192 + n * 512];
#pragma unroll
    for (int m = 0; m < 4; ++m) av[m] = *(const s16x8*)&lds[cb + abase + 8192 + m * 512];
    STAGE(T + 2, 0, 0);
    __builtin_amdgcn_s_barrier();
    asm volatile("s_waitcnt lgkmcnt(0)" ::: "memory");
    __builtin_amdgcn_s_setprio(1);
#pragma unroll
    for (int m = 0; m < 4; ++m)
#pragma unroll
      for (int n = 0; n < 4; ++n)
        acc[m][n] = __builtin_amdgcn_mfma_f32_16x16x32_bf16(av[m], bv[n], acc[m][n], 0, 0, 0);
    __builtin_amdgcn_s_setprio(0);
    __builtin_amdgcn_s_barrier();
    // ---- q3: A m4-7 kh1 ----
#pragma unroll
    for (int m = 0; m < 4; ++m) av[m] = *(const s16x8*)&lds[cb + abase + 8192 + 2048 + m * 512];
    STAGE(T + 2, 1, 1);
    if (drain)
      asm volatile("s_waitcnt vmcnt(0)" ::: "memory");
    else
      asm volatile("s_waitcnt vmcnt(6)" ::: "memory");
    __builtin_amdgcn_s_barrier();
    asm volatile("s_waitcnt lgkmcnt(0)" ::: "memory");
    __builtin_amdgcn_s_setprio(1);
#pragma unroll
    for (int m = 0; m < 4; ++m)
#pragma unroll
      for (int n = 0; n < 4; ++n)
        acc[m + 4][n] = __builtin_amdgcn_mfma_f32_16x16x32_bf16(av[m], bv[n], acc[m + 4][n], 0, 0, 0);
    __builtin_amdgcn_s_setprio(0);
    __builtin_amdgcn_s_barrier();
  };

#pragma unroll 1
  for (int T = 0; T < NT; T += 2) {
    TILE(T, 0, T == NT - 2);
    TILE(T + 1, 1, T + 1 == NT - 1);
  }

  const size_t zc = (size_t)bz * cZ;
#pragma unroll
  for (int m = 0; m < 8; ++m)
#pragma unroll
    for (int n = 0; n < 4; ++n)
#pragma unroll
      for (int r = 0; r < 4; ++r) {
        int row = bm * 256 + wr * 128 + m * 16 + (lane >> 4) * 4 + r;
        int col = bn * 256 + wc * 64 + n * 16 + fr;
        float f = acc[m][n][r];
        if constexpr (EPI == 0) {
          ((u16*)Cp)[zc + (size_t)row * ldc + col] = f2bf(f);
        } else if constexpr (EPI == 1 || EPI == 3) {
          ((float*)Cp)[zc + (size_t)row * ldc + col] = f * scale;
        } else {
          // qkv slab: 4 batch-pair slabs of 8,388,608 u16: [qh|ql|kh|kl]
          int bp = row >> 12;
          int rl = row & 4095;
          u16* slab = (u16*)Cp + (size_t)bp * 8388608;
          u16 h = f2bf(f);
          u16 l = f2bf(f - bf2f(h));
          if (col < 512) {
            slab[(size_t)rl * 512 + col] = h;
            slab[2097152 + (size_t)rl * 512 + col] = l;
          } else {
            slab[4194304 + (size_t)rl * 512 + (col - 512)] = h;
            slab[6291456 + (size_t)rl * 512 + (col - 512)] = l;
          }
        }
      }
}

// ---------------- row softmax + dropout mask -> P bf16 (4 batches / dispatch) ----
__global__ __launch_bounds__(256) void k_softmax(const float* __restrict__ sc,
                                                 u16* __restrict__ P,
                                                 const int* __restrict__ mask, int bp2) {
  const int rowp = blockIdx.x;  // 0..8191 (4 batches x 2048 rows)
  const int b = bp2 * 4 + (rowp >> 11), t = rowp & 2047;
  const float* srow = sc + (size_t)rowp * 2048;
  u16* prow = P + (size_t)b * 4194304 + (size_t)t * 2048;
  const int* mrow = mask + ((size_t)b * 2048 + t) * 2048;
  const int tid = threadIdx.x;
  float v[8];
#pragma unroll
  for (int j = 0; j < 8; ++j) v[j] = srow[tid + 256 * j];
  float m = v[0];
#pragma unroll
  for (int j = 1; j < 8; ++j) m = fmaxf(m, v[j]);
#pragma unroll
  for (int o = 32; o >= 1; o >>= 1) m = fmaxf(m, __shfl_xor(m, o));
  __shared__ float redm[4], reds[4];
  if ((tid & 63) == 0) redm[tid >> 6] = m;
  __syncthreads();
  m = fmaxf(fmaxf(redm[0], redm[1]), fmaxf(redm[2], redm[3]));
  float e[8], s = 0.f;
#pragma unroll
  for (int j = 0; j < 8; ++j) { e[j] = __expf(v[j] - m); s += e[j]; }
#pragma unroll
  for (int o = 32; o >= 1; o >>= 1) s += __shfl_xor(s, o);
  if ((tid & 63) == 0) reds[tid >> 6] = s;
  __syncthreads();
  s = reds[0] + reds[1] + reds[2] + reds[3];
  const float inv = 1.0f / (0.8f * s);
#pragma unroll
  for (int j = 0; j < 8; ++j) {
    int idx = tid + 256 * j;
    prow[idx] = mrow[idx] ? f2bf(e[j] * inv) : (u16)0;
  }
}

extern "C" void kernel_launch(void* const* d_in, const int* in_sizes, int n_in,
                              void* d_out, int out_size, void* d_ws, size_t ws_size,
                              hipStream_t stream) {
  const float* x  = (const float*)d_in[0];
  const float* Wq = (const float*)d_in[1];
  const float* Wk = (const float*)d_in[2];
  const float* Wv = (const float*)d_in[3];
  const int* mask = (const int*)d_in[4];
  float* out = (float*)d_out;

  // ws layout (u16 elements), total ~174 MB:
  u16* ws = (u16*)d_ws;
  u16* xh     = ws;                           // 16384x1024
  u16* xl     = xh + (size_t)16777216;
  u16* Whqk   = xl + (size_t)16777216;        // 1024x1024 (Wq rows 0-511 | Wk rows 512-1023)
  u16* Wlqk   = Whqk + (size_t)1048576;
  u16* Wvh    = Wlqk + (size_t)1048576;       // 1024x1024 plain bf16
  u16* qkslab = Wvh + (size_t)1048576;        // 4 slabs x 8388608 (later: P, 8x2048x2048)
  u16* vvt    = qkslab + (size_t)33554432;    // 1024 x 16384 (v^T, all batches)
  float* sc   = (float*)d_ws;                 // 4x2048x2048 fp32 = 67 MB, aliases xh+xl
                                              // (dead after QKV + vT GEMMs)

  k_cast_split<<<16384, 256, 0, stream>>>(x, xh, xl, 4194304);
  k_cast_split<<<512, 256, 0, stream>>>(Wq, Whqk, Wlqk, 131072);
  k_cast_split<<<512, 256, 0, stream>>>(Wk, Whqk + 524288, Wlqk + 524288, 131072);
  k_cast_plain<<<1024, 256, 0, stream>>>(Wv, Wvh, 262144);

  // q,k = x @ [Wq|Wk]^T  (3-term split folded into K: K_eff = 3072)
  dim3 gqk(4, 64, 1);
  k_gemm<3, 1024, 2><<<gqk, 512, 0, stream>>>(xh, xl, 1024, 0, Whqk, Wlqk, 1024, 0,
                                              qkslab, 0, 0, 0.f);

  // v^T = Wv @ x^T (plain bf16): C[g][t], coalesced
  dim3 gvt(64, 4, 1);
  k_gemm<1, 1024, 0><<<gvt, 512, 0, stream>>>(Wvh, (u16*)0, 1024, 0, xh, (u16*)0, 1024, 0,
                                              vvt, 16384, 0, 0.f);

  const float scale = 0.044194173824159216f;  // 1/sqrt(512)
  for (int bp2 = 0; bp2 < 2; ++bp2) {
    // scores for 4 batches (2 slabs), split-as-K (K_eff = 1536), z in [0,4)
    dim3 gs(8, 8, 4);
    k_gemm<3, 512, 3><<<gs, 512, 0, stream>>>(qkslab + (size_t)bp2 * 16777216, (u16*)0, 512, 0,
                                              (u16*)0, (u16*)0, 512, 0,
                                              sc, 2048, 4194304, scale);
    // softmax overwrites the (now dead) q/k slabs with P bf16 (linear per batch)
    k_softmax<<<8192, 256, 0, stream>>>(sc, qkslab, mask, bp2);
  }

  // out = P @ (v^T)^T for all 8 batches in one launch
  dim3 gpv(4, 8, 8);
  k_gemm<1, 2048, 1><<<gpv, 512, 0, stream>>>(qkslab, (u16*)0, 2048, 4194304,
                                              vvt, (u16*)0, 16384, 2048,
                                              out, 1024, 2097152, 1.0f);

  (void)in_sizes; (void)n_in; (void)out_size; (void)ws_size;
}